// Round 2
// baseline (105.751 us; speedup 1.0000x reference)
//
#include <hip/hip_runtime.h>
#include <math.h>

// Fused HybridEstimatorQNN forward:
//   q  = sin(x0) * sin(x1 + w)
//   h1 = tanh([x0,x1,q] @ W1 + b1)   (3->8)
//   h2 = tanh(h1 @ W2 + b2)          (8->4)
//   out = h2 @ W3 + b3               (4->1)
//
// R2: rational tanh (1 rcp, no exp2) + 2 elems/thread (low VGPR pressure).

// Lambert continued-fraction order-7 rational tanh.
// |err| < 2e-5 for |x| <= 4; ratio grows past 1 for large |x| -> clamp.
__device__ __forceinline__ float fast_tanh(float x) {
    float t = x * x;
    float n = fmaf(fmaf(t + 378.0f, t, 17325.0f), t, 135135.0f);
    float d = fmaf(fmaf(fmaf(28.0f, t, 3150.0f), t, 62370.0f), t, 135135.0f);
    float r = x * n * __builtin_amdgcn_rcpf(d);
    return fminf(1.0f, fmaxf(-1.0f, r));   // v_med3_f32
}

__device__ __forceinline__ float fast_sin(float x) {
    // v_sin_f32 takes revolutions; inputs ~N(0,1)(+w), well in range.
    return __builtin_amdgcn_sinf(x * 0.15915494309189535f);
}

__global__ __launch_bounds__(256) void qnn_fused_kernel(
    const float* __restrict__ in,   // [n,2]
    const float* __restrict__ W1,   // [3,8]
    const float* __restrict__ b1,   // [8]
    const float* __restrict__ W2,   // [8,4]
    const float* __restrict__ b2,   // [4]
    const float* __restrict__ W3,   // [4,1]
    const float* __restrict__ b3,   // [1]
    const float* __restrict__ wq,   // [1]
    float* __restrict__ out,        // [n]
    int n)
{
    // ---- hoist params (uniform addresses -> scalar/SGPR loads) ----
    const float w = wq[0];
    float w1[3][8];
#pragma unroll
    for (int i = 0; i < 3; ++i)
#pragma unroll
        for (int j = 0; j < 8; ++j) w1[i][j] = W1[i * 8 + j];
    float bb1[8];
#pragma unroll
    for (int j = 0; j < 8; ++j) bb1[j] = b1[j];
    float w2[8][4];
#pragma unroll
    for (int i = 0; i < 8; ++i)
#pragma unroll
        for (int j = 0; j < 4; ++j) w2[i][j] = W2[i * 4 + j];
    float bb2[4];
#pragma unroll
    for (int j = 0; j < 4; ++j) bb2[j] = b2[j];
    float w3[4];
#pragma unroll
    for (int i = 0; i < 4; ++i) w3[i] = W3[i];
    const float bb3 = b3[0];

    auto forward = [&](float x0, float x1) -> float {
        float q = fast_sin(x0) * fast_sin(x1 + w);
        float h1[8];
#pragma unroll
        for (int j = 0; j < 8; ++j) {
            float acc = fmaf(x0, w1[0][j],
                        fmaf(x1, w1[1][j],
                        fmaf(q,  w1[2][j], bb1[j])));
            h1[j] = fast_tanh(acc);
        }
        float h2[4];
#pragma unroll
        for (int j = 0; j < 4; ++j) {
            float acc = bb2[j];
#pragma unroll
            for (int i = 0; i < 8; ++i) acc = fmaf(h1[i], w2[i][j], acc);
            h2[j] = fast_tanh(acc);
        }
        float o = bb3;
#pragma unroll
        for (int i = 0; i < 4; ++i) o = fmaf(h2[i], w3[i], o);
        return o;
    };

    const int base = (blockIdx.x * blockDim.x + threadIdx.x) * 2;
    if (base + 1 < n) {
        const float4 p = *reinterpret_cast<const float4*>(in + 2 * base);
        float2 o;
        o.x = forward(p.x, p.y);
        o.y = forward(p.z, p.w);
        *reinterpret_cast<float2*>(out + base) = o;
    } else if (base < n) {
        out[base] = forward(in[2 * base], in[2 * base + 1]);
    }
}

extern "C" void kernel_launch(void* const* d_in, const int* in_sizes, int n_in,
                              void* d_out, int out_size, void* d_ws, size_t ws_size,
                              hipStream_t stream) {
    const float* in = (const float*)d_in[0];
    const float* W1 = (const float*)d_in[1];
    const float* b1 = (const float*)d_in[2];
    const float* W2 = (const float*)d_in[3];
    const float* b2 = (const float*)d_in[4];
    const float* W3 = (const float*)d_in[5];
    const float* b3 = (const float*)d_in[6];
    const float* wq = (const float*)d_in[7];
    float* out = (float*)d_out;

    const int n = out_size;                 // B rows
    const int threads = 256;
    const int elems_per_block = threads * 2;
    const int blocks = (n + elems_per_block - 1) / elems_per_block;

    hipLaunchKernelGGL(qnn_fused_kernel, dim3(blocks), dim3(threads), 0, stream,
                       in, W1, b1, W2, b2, W3, b3, wq, out, n);
}

// Round 3
// 101.682 us; speedup vs baseline: 1.0400x; 1.0400x over previous
//
#include <hip/hip_runtime.h>
#include <math.h>

// Fused HybridEstimatorQNN forward:
//   q  = sin(x0) * sin(x1 + w)
//   h1 = tanh([x0,x1,q] @ W1 + b1)   (3->8)
//   h2 = tanh(h1 @ W2 + b2)          (8->4)
//   out = h2 @ W3 + b3               (4->1)
//
// R3: SIMD-within-thread — process the thread's 2 elements as float2
// ext-vectors so the compiler emits VOP3P v_pk_fma_f32 / v_pk_mul_f32
// (2 fp32 ops per instruction). Transcendentals (rcp/sin) scalarized.

typedef float f32x2 __attribute__((ext_vector_type(2)));

__device__ __forceinline__ f32x2 pk_fma(f32x2 a, f32x2 b, f32x2 c) {
    return __builtin_elementwise_fma(a, b, c);
}

// Lambert continued-fraction order-7 rational tanh, packed over 2 lanes.
// |err| < 2e-5 for |x| <= 4; clamp handles the tail.
__device__ __forceinline__ f32x2 fast_tanh2(f32x2 x) {
    f32x2 t = x * x;
    f32x2 n = pk_fma(pk_fma(t, (f32x2)1.0f, (f32x2)378.0f) * t + (f32x2)17325.0f,
                     t, (f32x2)135135.0f);
    // n = ((t + 378)*t + 17325)*t + 135135
    f32x2 d = pk_fma(pk_fma(pk_fma((f32x2)28.0f, t, (f32x2)3150.0f), t,
                            (f32x2)62370.0f), t, (f32x2)135135.0f);
    f32x2 r;
    r.x = __builtin_amdgcn_rcpf(d.x);
    r.y = __builtin_amdgcn_rcpf(d.y);
    f32x2 v = x * n * r;
    v = __builtin_elementwise_min(v, (f32x2)1.0f);
    v = __builtin_elementwise_max(v, (f32x2)-1.0f);
    return v;
}

__device__ __forceinline__ f32x2 fast_sin2(f32x2 x) {
    f32x2 rev = x * 0.15915494309189535f;
    f32x2 s;
    s.x = __builtin_amdgcn_sinf(rev.x);
    s.y = __builtin_amdgcn_sinf(rev.y);
    return s;
}

__global__ __launch_bounds__(256) void qnn_fused_kernel(
    const float* __restrict__ in,   // [n,2]
    const float* __restrict__ W1,   // [3,8]
    const float* __restrict__ b1,   // [8]
    const float* __restrict__ W2,   // [8,4]
    const float* __restrict__ b2,   // [4]
    const float* __restrict__ W3,   // [4,1]
    const float* __restrict__ b3,   // [1]
    const float* __restrict__ wq,   // [1]
    float* __restrict__ out,        // [n]
    int n)
{
    // ---- hoist params (uniform addresses -> scalar/SGPR loads) ----
    const float w = wq[0];
    float w1[3][8];
#pragma unroll
    for (int i = 0; i < 3; ++i)
#pragma unroll
        for (int j = 0; j < 8; ++j) w1[i][j] = W1[i * 8 + j];
    float bb1[8];
#pragma unroll
    for (int j = 0; j < 8; ++j) bb1[j] = b1[j];
    float w2[8][4];
#pragma unroll
    for (int i = 0; i < 8; ++i)
#pragma unroll
        for (int j = 0; j < 4; ++j) w2[i][j] = W2[i * 4 + j];
    float bb2[4];
#pragma unroll
    for (int j = 0; j < 4; ++j) bb2[j] = b2[j];
    float w3[4];
#pragma unroll
    for (int i = 0; i < 4; ++i) w3[i] = W3[i];
    const float bb3 = b3[0];

    // forward for a PAIR of elements, vectorized across the pair
    auto forward2 = [&](f32x2 x0, f32x2 x1) -> f32x2 {
        f32x2 q = fast_sin2(x0) * fast_sin2(x1 + (f32x2)w);
        f32x2 h1[8];
#pragma unroll
        for (int j = 0; j < 8; ++j) {
            f32x2 acc = pk_fma(x0, (f32x2)w1[0][j],
                        pk_fma(x1, (f32x2)w1[1][j],
                        pk_fma(q,  (f32x2)w1[2][j], (f32x2)bb1[j])));
            h1[j] = fast_tanh2(acc);
        }
        f32x2 h2[4];
#pragma unroll
        for (int j = 0; j < 4; ++j) {
            f32x2 acc = (f32x2)bb2[j];
#pragma unroll
            for (int i = 0; i < 8; ++i) acc = pk_fma(h1[i], (f32x2)w2[i][j], acc);
            h2[j] = fast_tanh2(acc);
        }
        f32x2 o = (f32x2)bb3;
#pragma unroll
        for (int i = 0; i < 4; ++i) o = pk_fma(h2[i], (f32x2)w3[i], o);
        return o;
    };

    const int base = (blockIdx.x * blockDim.x + threadIdx.x) * 2;
    if (base + 1 < n) {
        const float4 p = *reinterpret_cast<const float4*>(in + 2 * base);
        f32x2 x0 = {p.x, p.z};
        f32x2 x1 = {p.y, p.w};
        f32x2 o = forward2(x0, x1);
        float2 ov = {o.x, o.y};
        *reinterpret_cast<float2*>(out + base) = ov;
    } else if (base < n) {
        f32x2 x0 = (f32x2)in[2 * base];
        f32x2 x1 = (f32x2)in[2 * base + 1];
        f32x2 o = forward2(x0, x1);
        out[base] = o.x;
    }
}

extern "C" void kernel_launch(void* const* d_in, const int* in_sizes, int n_in,
                              void* d_out, int out_size, void* d_ws, size_t ws_size,
                              hipStream_t stream) {
    const float* in = (const float*)d_in[0];
    const float* W1 = (const float*)d_in[1];
    const float* b1 = (const float*)d_in[2];
    const float* W2 = (const float*)d_in[3];
    const float* b2 = (const float*)d_in[4];
    const float* W3 = (const float*)d_in[5];
    const float* b3 = (const float*)d_in[6];
    const float* wq = (const float*)d_in[7];
    float* out = (float*)d_out;

    const int n = out_size;                 // B rows
    const int threads = 256;
    const int elems_per_block = threads * 2;
    const int blocks = (n + elems_per_block - 1) / elems_per_block;

    hipLaunchKernelGGL(qnn_fused_kernel, dim3(blocks), dim3(threads), 0, stream,
                       in, W1, b1, W2, b2, W3, b3, wq, out, n);
}